// Round 1
// baseline (314.469 us; speedup 1.0000x reference)
//
#include <hip/hip_runtime.h>
#include <float.h>

typedef __bf16 bf16x8 __attribute__((ext_vector_type(8)));
typedef __bf16 bf16x2 __attribute__((ext_vector_type(2)));
typedef float  f32x4  __attribute__((ext_vector_type(4)));

#define G      256
#define MT     64      // points per tile
#define H1DIM  64
#define H2DIM  128
#define LAT    256
#define H1PAD  72      // 144 B rows: 16B-aligned, stride 36 dw == 4 mod 32
#define H2PAD  136     // 272 B rows: 16B-aligned, stride 68 dw == 4 mod 32

// order-preserving float->uint map (monotone): max on uints == max on floats
__device__ __forceinline__ unsigned mapf(float f) {
  unsigned u = __float_as_uint(f);
  return (u & 0x80000000u) ? ~u : (u | 0x80000000u);
}
__device__ __forceinline__ float unmapf(unsigned u) {
  return (u & 0x80000000u) ? __uint_as_float(u & 0x7fffffffu) : __uint_as_float(~u);
}

// ---------------- centroids: segment mean of pos (cols 1..3) ----------------
__global__ void centroid_kernel(const float* __restrict__ pc, const int* __restrict__ sid,
                                float* __restrict__ sums, int n) {
  __shared__ float ls[G * 4];
  for (int i = threadIdx.x; i < G * 4; i += blockDim.x) ls[i] = 0.f;
  __syncthreads();
  int stride = gridDim.x * blockDim.x;
  for (int p = blockIdx.x * blockDim.x + threadIdx.x; p < n; p += stride) {
    int s = sid[p];
    float px = pc[p * 5 + 1], py = pc[p * 5 + 2], pz = pc[p * 5 + 3];
    int s0 = __shfl(s, 0);
    unsigned long long bal = __ballot(s == s0);
    if (bal == ~0ull) {   // whole wave same segment (sorted ids): butterfly reduce
      #pragma unroll
      for (int off = 1; off < 64; off <<= 1) {
        px += __shfl_xor(px, off);
        py += __shfl_xor(py, off);
        pz += __shfl_xor(pz, off);
      }
      if ((threadIdx.x & 63) == 0) {
        atomicAdd(&ls[s0 * 4 + 0], px);
        atomicAdd(&ls[s0 * 4 + 1], py);
        atomicAdd(&ls[s0 * 4 + 2], pz);
        atomicAdd(&ls[s0 * 4 + 3], 64.f);
      }
    } else {
      atomicAdd(&ls[s * 4 + 0], px);
      atomicAdd(&ls[s * 4 + 1], py);
      atomicAdd(&ls[s * 4 + 2], pz);
      atomicAdd(&ls[s * 4 + 3], 1.f);
    }
  }
  __syncthreads();
  for (int i = threadIdx.x; i < G * 4; i += blockDim.x)
    if (ls[i] != 0.f) atomicAdd(&sums[i], ls[i]);
}

// ---------------- fused MLP + segment max ----------------
// block = 256 thr (4 waves); waves arranged 2 (row-groups) x 2 (col-groups).
// W2/W3 live in registers as persistent MFMA B-fragments; activations via LDS.
__global__ __launch_bounds__(256, 1) void mlp_kernel(
    const float* __restrict__ pc,
    const float* __restrict__ W1, const float* __restrict__ b1,
    const float* __restrict__ W2, const float* __restrict__ b2,
    const float* __restrict__ W3, const float* __restrict__ b3,
    const int* __restrict__ sid,
    unsigned* __restrict__ pooled,
    int n, int tiles_per_block) {
  __shared__ __align__(16) float  feats4[MT][4];
  __shared__ __align__(16) __bf16 sh1[MT][H1PAD];
  __shared__ __align__(16) __bf16 sh2[MT][H2PAD];
  __shared__ int      segt[MT];
  __shared__ unsigned runmax[LAT];

  const int t    = threadIdx.x;
  const int lane = t & 63;
  const int wave = t >> 6;
  const int q    = lane >> 4;
  const int nn   = lane & 15;
  const int wrow = wave & 1;   // row-group: rows [wrow*32, wrow*32+32)
  const int wcol = wave >> 1;  // col-group

  for (int i = t; i < LAT; i += 256) runmax[i] = 0u;

  // layer-1 per-thread weight slice: thread handles 4 points x 4 cols
  float w1r[4][4], b1r[4];
  {
    int nb = (t >> 4) * 4;
    #pragma unroll
    for (int j = 0; j < 4; ++j)
      #pragma unroll
      for (int ni = 0; ni < 4; ++ni) w1r[j][ni] = W1[j * H1DIM + nb + ni];
    #pragma unroll
    for (int ni = 0; ni < 4; ++ni) b1r[ni] = b1[nb + ni];
  }

  // persistent L2 B-frags: B[k][n], n = lane&15, k = q*8+j (+ks*32)
  bf16x8 w2f[4][2];
  float  b2r[4];
  #pragma unroll
  for (int ct = 0; ct < 4; ++ct) {
    int col = wcol * 64 + ct * 16 + nn;
    b2r[ct] = b2[col];
    #pragma unroll
    for (int ks = 0; ks < 2; ++ks)
      #pragma unroll
      for (int j = 0; j < 8; ++j)
        w2f[ct][ks][j] = (__bf16)W2[(ks * 32 + q * 8 + j) * H2DIM + col];
  }
  // persistent L3 B-frags
  bf16x8 w3f[8][4];
  float  b3r[8];
  #pragma unroll
  for (int ct = 0; ct < 8; ++ct) {
    int col = wcol * 128 + ct * 16 + nn;
    b3r[ct] = b3[col];
    #pragma unroll
    for (int ks = 0; ks < 4; ++ks)
      #pragma unroll
      for (int j = 0; j < 8; ++j)
        w3f[ct][ks][j] = (__bf16)W3[(ks * 32 + q * 8 + j) * LAT + col];
  }

  const int tile0 = blockIdx.x * tiles_per_block;
  int first = tile0 * MT; if (first > n - 1) first = n - 1;
  int s_cur = sid[first];
  __syncthreads();

  for (int ti = 0; ti < tiles_per_block; ++ti) {
    const int base = (tile0 + ti) * MT;
    if (base >= n) break;

    // ---- stage points + seg ids (one wave's worth of lanes) ----
    if (t < MT) {
      int p = base + t;
      int pcl = (p < n) ? p : (n - 1);
      feats4[t][0] = pc[pcl * 5 + 4];  // x first (concat order!)
      feats4[t][1] = pc[pcl * 5 + 1];
      feats4[t][2] = pc[pcl * 5 + 2];
      feats4[t][3] = pc[pcl * 5 + 3];
      segt[t] = sid[pcl];
    }
    __syncthreads();

    // ---- layer 1 (fp32 VALU), write bf16 to LDS ----
    {
      int tm = t & 15;
      #pragma unroll
      for (int mi = 0; mi < 4; ++mi) {
        int m = tm * 4 + mi;
        float f0 = feats4[m][0], f1 = feats4[m][1], f2 = feats4[m][2], f3 = feats4[m][3];
        #pragma unroll
        for (int np = 0; np < 2; ++np) {
          int ni0 = np * 2;
          float v0 = fmaxf(b1r[ni0]     + f0*w1r[0][ni0]     + f1*w1r[1][ni0]     + f2*w1r[2][ni0]     + f3*w1r[3][ni0],     0.f);
          float v1 = fmaxf(b1r[ni0 + 1] + f0*w1r[0][ni0 + 1] + f1*w1r[1][ni0 + 1] + f2*w1r[2][ni0 + 1] + f3*w1r[3][ni0 + 1], 0.f);
          bf16x2 pr; pr[0] = (__bf16)v0; pr[1] = (__bf16)v1;
          int nbase = (t >> 4) * 4 + ni0;
          *reinterpret_cast<bf16x2*>(&sh1[m][nbase]) = pr;
        }
      }
    }
    __syncthreads();

    // ---- layer 2 MFMA: (64x64) @ (64x128) ----
    f32x4 a2[2][4];
    f32x4 zero4 = {0.f, 0.f, 0.f, 0.f};
    #pragma unroll
    for (int rt = 0; rt < 2; ++rt)
      #pragma unroll
      for (int ct = 0; ct < 4; ++ct) a2[rt][ct] = zero4;
    #pragma unroll
    for (int ks = 0; ks < 2; ++ks) {
      bf16x8 af[2];
      #pragma unroll
      for (int rt = 0; rt < 2; ++rt)
        af[rt] = *reinterpret_cast<const bf16x8*>(&sh1[wrow * 32 + rt * 16 + nn][ks * 32 + q * 8]);
      #pragma unroll
      for (int rt = 0; rt < 2; ++rt)
        #pragma unroll
        for (int ct = 0; ct < 4; ++ct)
          a2[rt][ct] = __builtin_amdgcn_mfma_f32_16x16x32_bf16(af[rt], w2f[ct][ks], a2[rt][ct], 0, 0, 0);
    }
    // relu + bias -> LDS (C/D layout: col=lane&15, row=q*4+reg)
    #pragma unroll
    for (int rt = 0; rt < 2; ++rt)
      #pragma unroll
      for (int ct = 0; ct < 4; ++ct)
        #pragma unroll
        for (int r = 0; r < 4; ++r) {
          float v = fmaxf(a2[rt][ct][r] + b2r[ct], 0.f);
          sh2[wrow * 32 + rt * 16 + q * 4 + r][wcol * 64 + ct * 16 + nn] = (__bf16)v;
        }
    __syncthreads();

    // ---- layer 3 MFMA: (64x128) @ (128x256) ----
    f32x4 a3[2][8];
    #pragma unroll
    for (int rt = 0; rt < 2; ++rt)
      #pragma unroll
      for (int ct = 0; ct < 8; ++ct) a3[rt][ct] = zero4;
    #pragma unroll
    for (int ks = 0; ks < 4; ++ks) {
      bf16x8 af[2];
      #pragma unroll
      for (int rt = 0; rt < 2; ++rt)
        af[rt] = *reinterpret_cast<const bf16x8*>(&sh2[wrow * 32 + rt * 16 + nn][ks * 32 + q * 8]);
      #pragma unroll
      for (int rt = 0; rt < 2; ++rt)
        #pragma unroll
        for (int ct = 0; ct < 8; ++ct)
          a3[rt][ct] = __builtin_amdgcn_mfma_f32_16x16x32_bf16(af[rt], w3f[ct][ks], a3[rt][ct], 0, 0, 0);
    }

    // ---- segment max (ids sorted; block-uniform control) ----
    int smin = segt[0], smax = segt[MT - 1];
    if (smin == s_cur && smax == s_cur) {
      // fast path: whole tile in current segment
      #pragma unroll
      for (int ct = 0; ct < 8; ++ct) {
        float mx = -FLT_MAX;
        #pragma unroll
        for (int rt = 0; rt < 2; ++rt)
          #pragma unroll
          for (int r = 0; r < 4; ++r) {
            int row = wrow * 32 + rt * 16 + q * 4 + r;
            float val = a3[rt][ct][r] + b3r[ct];
            mx = fmaxf(mx, (base + row < n) ? val : -FLT_MAX);
          }
        mx = fmaxf(mx, __shfl_xor(mx, 16));
        mx = fmaxf(mx, __shfl_xor(mx, 32));
        if (q == 0 && mx > -FLT_MAX)
          atomicMax(&runmax[wcol * 128 + ct * 16 + nn], mapf(mx));
      }
    } else {
      // slow path (segment boundary; ~255 occurrences total)
      if (smin != s_cur) {
        __syncthreads();
        unsigned u = runmax[t];
        if (u) { atomicMax(&pooled[s_cur * LAT + t], u); runmax[t] = 0u; }
        __syncthreads();
      }
      int  srow[8]; bool vrow[8];
      #pragma unroll
      for (int k = 0; k < 8; ++k) {
        int row = wrow * 32 + (k >> 2) * 16 + q * 4 + (k & 3);
        srow[k] = segt[row];
        vrow[k] = (base + row) < n;
      }
      for (int s = smin; s <= smax; ++s) {
        #pragma unroll
        for (int ct = 0; ct < 8; ++ct) {
          float mx = -FLT_MAX;
          #pragma unroll
          for (int k = 0; k < 8; ++k) {
            float val = a3[k >> 2][ct][k & 3] + b3r[ct];
            mx = fmaxf(mx, (vrow[k] && srow[k] == s) ? val : -FLT_MAX);
          }
          mx = fmaxf(mx, __shfl_xor(mx, 16));
          mx = fmaxf(mx, __shfl_xor(mx, 32));
          if (q == 0 && mx > -FLT_MAX)
            atomicMax(&runmax[wcol * 128 + ct * 16 + nn], mapf(mx));
        }
        if (s < smax) {     // segment s is complete: flush to global
          __syncthreads();
          unsigned u = runmax[t];
          if (u) { atomicMax(&pooled[s * LAT + t], u); runmax[t] = 0u; }
          __syncthreads();
        }
      }
      s_cur = smax;
    }
    __syncthreads();
  }
  // final flush of the running segment
  {
    unsigned u = runmax[t];
    if (u) atomicMax(&pooled[s_cur * LAT + t], u);
  }
}

// ---------------- head: pooled @ Wf + bf -> softplus, + centroid ----------------
__global__ void final_kernel(const float* __restrict__ sums, const unsigned* __restrict__ pooled,
                             const float* __restrict__ Wf, const float* __restrict__ bfv,
                             float* __restrict__ out) {
  __shared__ float red[4][3];
  int g = blockIdx.x;
  int t = threadIdx.x;   // 256 = LAT
  unsigned u = pooled[g * LAT + t];
  float f = u ? unmapf(u) : 0.f;
  float s0 = f * Wf[t * 3 + 0];
  float s1 = f * Wf[t * 3 + 1];
  float s2 = f * Wf[t * 3 + 2];
  #pragma unroll
  for (int off = 1; off < 64; off <<= 1) {
    s0 += __shfl_xor(s0, off);
    s1 += __shfl_xor(s1, off);
    s2 += __shfl_xor(s2, off);
  }
  int wave = t >> 6;
  if ((t & 63) == 0) { red[wave][0] = s0; red[wave][1] = s1; red[wave][2] = s2; }
  __syncthreads();
  if (t < 3) {
    float acc = bfv[t] + red[0][t] + red[1][t] + red[2][t] + red[3][t];
    float sp  = fmaxf(acc, 0.f) + log1pf(expf(-fabsf(acc)));
    float cnt = fmaxf(sums[g * 4 + 3], 1.f);
    float cen = sums[g * 4 + t] / cnt;
    out[g * 3 + t] = cen + sp;
  }
}

extern "C" void kernel_launch(void* const* d_in, const int* in_sizes, int n_in,
                              void* d_out, int out_size, void* d_ws, size_t ws_size,
                              hipStream_t stream) {
  const float* pc  = (const float*)d_in[0];
  const float* W1  = (const float*)d_in[1];
  const float* b1  = (const float*)d_in[2];
  const float* W2  = (const float*)d_in[3];
  const float* b2  = (const float*)d_in[4];
  const float* W3  = (const float*)d_in[5];
  const float* b3  = (const float*)d_in[6];
  const float* Wf  = (const float*)d_in[7];
  const float* bfv = (const float*)d_in[8];
  const int*   sid = (const int*)d_in[9];
  int n = in_sizes[0] / 5;

  float*    sums   = (float*)d_ws;                         // G*4 fp32 (pos sums + count)
  unsigned* pooled = (unsigned*)((char*)d_ws + 4096);      // G*LAT mapped-uint maxes
  hipMemsetAsync(d_ws, 0, 4096 + (size_t)G * LAT * 4, stream);

  centroid_kernel<<<1024, 256, 0, stream>>>(pc, sid, sums, n);

  int tiles   = (n + MT - 1) / MT;
  int nblocks = 512;
  int tpb     = (tiles + nblocks - 1) / nblocks;
  mlp_kernel<<<nblocks, 256, 0, stream>>>(pc, W1, b1, W2, b2, W3, b3, sid, pooled, n, tpb);

  final_kernel<<<G, 256, 0, stream>>>(sums, pooled, Wf, bfv, (float*)d_out);
}

// Round 2
// 306.492 us; speedup vs baseline: 1.0260x; 1.0260x over previous
//
#include <hip/hip_runtime.h>
#include <float.h>

typedef __bf16 bf16x8 __attribute__((ext_vector_type(8)));
typedef __bf16 bf16x4 __attribute__((ext_vector_type(4)));
typedef float  f32x4  __attribute__((ext_vector_type(4)));

#define G      256
#define MT     32      // points per tile
#define H1DIM  64
#define H2DIM  128
#define LAT    256
#define H1PAD  72      // 144 B rows: 16B-aligned, 36 dw == 4 mod 32 -> conflict-free b128
#define H2PAD  136     // 272 B rows: 16B-aligned, 68 dw == 4 mod 32 -> conflict-free b128

// order-preserving float->uint map: max on uints == max on floats
__device__ __forceinline__ unsigned mapf(float f) {
  unsigned u = __float_as_uint(f);
  return (u & 0x80000000u) ? ~u : (u | 0x80000000u);
}
__device__ __forceinline__ float unmapf(unsigned u) {
  return (u & 0x80000000u) ? __uint_as_float(u & 0x7fffffffu) : __uint_as_float(~u);
}

// ---------------- centroids: segment mean of pos (cols 1..3) ----------------
__global__ void centroid_kernel(const float* __restrict__ pc, const int* __restrict__ sid,
                                float* __restrict__ sums, int n) {
  __shared__ float ls[G * 4];
  for (int i = threadIdx.x; i < G * 4; i += blockDim.x) ls[i] = 0.f;
  __syncthreads();
  int stride = gridDim.x * blockDim.x;
  for (int p = blockIdx.x * blockDim.x + threadIdx.x; p < n; p += stride) {
    int s = sid[p];
    float px = pc[p * 5 + 1], py = pc[p * 5 + 2], pz = pc[p * 5 + 3];
    int s0 = __shfl(s, 0);
    unsigned long long bal = __ballot(s == s0);
    if (bal == ~0ull) {   // whole wave same segment (sorted ids)
      #pragma unroll
      for (int off = 1; off < 64; off <<= 1) {
        px += __shfl_xor(px, off);
        py += __shfl_xor(py, off);
        pz += __shfl_xor(pz, off);
      }
      if ((threadIdx.x & 63) == 0) {
        atomicAdd(&ls[s0 * 4 + 0], px);
        atomicAdd(&ls[s0 * 4 + 1], py);
        atomicAdd(&ls[s0 * 4 + 2], pz);
        atomicAdd(&ls[s0 * 4 + 3], 64.f);
      }
    } else {
      atomicAdd(&ls[s * 4 + 0], px);
      atomicAdd(&ls[s * 4 + 1], py);
      atomicAdd(&ls[s * 4 + 2], pz);
      atomicAdd(&ls[s * 4 + 3], 1.f);
    }
  }
  __syncthreads();
  for (int i = threadIdx.x; i < G * 4; i += blockDim.x)
    if (ls[i] != 0.f) atomicAdd(&sums[i], ls[i]);
}

// ---------------- fused MLP + segment max ----------------
// 256 thr = 4 waves. A-operand = weights (registers), B-operand = activations (LDS).
// Wave w owns out-features: L1 [w*16,+16), L2 [w*32,+32), L3 [w*64,+64); all 32 points.
// C/D layout: row (q*4+r) = out-feature, col (nn) = point -> packed b64 epilogue writes.
// Segment max: per-wave register running max, bias deferred to (rare) boundary flush.
__global__ __launch_bounds__(256, 3) void mlp_kernel(
    const float* __restrict__ pc,
    const float* __restrict__ W1, const float* __restrict__ b1,
    const float* __restrict__ W2, const float* __restrict__ b2,
    const float* __restrict__ W3, const float* __restrict__ b3,
    const int* __restrict__ sid,
    unsigned* __restrict__ pooled,
    int n, int tiles_per_block) {
  __shared__ __align__(16) __bf16 shF[MT][8];
  __shared__ __align__(16) __bf16 sh1[MT][H1PAD];
  __shared__ __align__(16) __bf16 sh2[MT][H2PAD];
  __shared__ int segt[MT];

  const int t  = threadIdx.x;
  const int w  = t >> 6;         // wave id 0..3
  const int lane = t & 63;
  const int q  = lane >> 4;
  const int nn = lane & 15;

  // ---- persistent weight fragments (A-operand: A[m=nn][k=q*8+j]) ----
  bf16x8 w1f;                    // L1, K=32 zero-padded (real K=4)
  #pragma unroll
  for (int j = 0; j < 8; ++j) {
    int k = q * 8 + j;
    w1f[j] = (k < 4) ? (__bf16)W1[k * H1DIM + w * 16 + nn] : (__bf16)0.f;
  }
  float b1r[4];
  #pragma unroll
  for (int r = 0; r < 4; ++r) b1r[r] = b1[w * 16 + q * 4 + r];

  bf16x8 w2f[2][2];              // [mt][ks]
  float  b2r[2][4];
  #pragma unroll
  for (int mt = 0; mt < 2; ++mt) {
    int m = w * 32 + mt * 16 + nn;
    #pragma unroll
    for (int ks = 0; ks < 2; ++ks)
      #pragma unroll
      for (int j = 0; j < 8; ++j)
        w2f[mt][ks][j] = (__bf16)W2[(ks * 32 + q * 8 + j) * H2DIM + m];
    #pragma unroll
    for (int r = 0; r < 4; ++r) b2r[mt][r] = b2[w * 32 + mt * 16 + q * 4 + r];
  }

  bf16x8 w3f[4][4];              // [mt][ks]
  #pragma unroll
  for (int mt = 0; mt < 4; ++mt) {
    int m = w * 64 + mt * 16 + nn;
    #pragma unroll
    for (int ks = 0; ks < 4; ++ks)
      #pragma unroll
      for (int j = 0; j < 8; ++j)
        w3f[mt][ks][j] = (__bf16)W3[(ks * 32 + q * 8 + j) * LAT + m];
  }

  float run[4][4];               // running segment max (bias NOT included)
  #pragma unroll
  for (int mt = 0; mt < 4; ++mt)
    #pragma unroll
    for (int r = 0; r < 4; ++r) run[mt][r] = -FLT_MAX;

  // flush helper: reduce over the 16 point-lanes, add bias, atomicMax to global
  auto flushvals = [&](float vals[4][4], int s) {
    #pragma unroll
    for (int mt = 0; mt < 4; ++mt)
      #pragma unroll
      for (int r = 0; r < 4; ++r) {
        int feat = w * 64 + mt * 16 + q * 4 + r;
        float v = vals[mt][r] + b3[feat];
        v = fmaxf(v, __shfl_xor(v, 1));
        v = fmaxf(v, __shfl_xor(v, 2));
        v = fmaxf(v, __shfl_xor(v, 4));
        v = fmaxf(v, __shfl_xor(v, 8));
        if (nn == 0) atomicMax(&pooled[s * LAT + feat], mapf(v));
      }
  };

  const int tile0 = blockIdx.x * tiles_per_block;
  int first = tile0 * MT; if (first > n - 1) first = n - 1;
  int s_cur = sid[first];
  const f32x4 zero4 = {0.f, 0.f, 0.f, 0.f};
  const bf16x8 zero8 = {};

  for (int ti = 0; ti < tiles_per_block; ++ti) {
    const int base = (tile0 + ti) * MT;
    if (base >= n) break;

    // ---- stage 32 points (clamped duplicates are harmless for max) ----
    if (t < MT) {
      int p = base + t;
      int pcl = (p < n) ? p : (n - 1);
      const float* pp = pc + (size_t)pcl * 5;
      bf16x8 v = {};
      v[0] = (__bf16)pp[4];   // x first (concat order!)
      v[1] = (__bf16)pp[1];
      v[2] = (__bf16)pp[2];
      v[3] = (__bf16)pp[3];
      *reinterpret_cast<bf16x8*>(&shF[t][0]) = v;
      segt[t] = sid[pcl];
    }
    __syncthreads();

    // ---- layer 1 (MFMA, K zero-padded) ----
    {
      f32x4 acc1[2];
      #pragma unroll
      for (int nt = 0; nt < 2; ++nt) {
        bf16x8 ld = *reinterpret_cast<const bf16x8*>(&shF[nt * 16 + nn][0]);
        bf16x8 af = (q == 0) ? ld : zero8;
        acc1[nt] = __builtin_amdgcn_mfma_f32_16x16x32_bf16(w1f, af, zero4, 0, 0, 0);
      }
      #pragma unroll
      for (int nt = 0; nt < 2; ++nt) {
        bf16x4 pk;
        #pragma unroll
        for (int r = 0; r < 4; ++r)
          pk[r] = (__bf16)fmaxf(acc1[nt][r] + b1r[r], 0.f);
        *reinterpret_cast<bf16x4*>(&sh1[nt * 16 + nn][w * 16 + q * 4]) = pk;
      }
    }
    __syncthreads();

    // ---- layer 2: (32x64) @ (64x128) ----
    {
      f32x4 acc2[2][2];
      #pragma unroll
      for (int mt = 0; mt < 2; ++mt)
        #pragma unroll
        for (int nt = 0; nt < 2; ++nt) acc2[mt][nt] = zero4;
      #pragma unroll
      for (int ks = 0; ks < 2; ++ks) {
        bf16x8 bfr[2];
        #pragma unroll
        for (int nt = 0; nt < 2; ++nt)
          bfr[nt] = *reinterpret_cast<const bf16x8*>(&sh1[nt * 16 + nn][ks * 32 + q * 8]);
        #pragma unroll
        for (int mt = 0; mt < 2; ++mt)
          #pragma unroll
          for (int nt = 0; nt < 2; ++nt)
            acc2[mt][nt] = __builtin_amdgcn_mfma_f32_16x16x32_bf16(w2f[mt][ks], bfr[nt], acc2[mt][nt], 0, 0, 0);
      }
      #pragma unroll
      for (int mt = 0; mt < 2; ++mt)
        #pragma unroll
        for (int nt = 0; nt < 2; ++nt) {
          bf16x4 pk;
          #pragma unroll
          for (int r = 0; r < 4; ++r)
            pk[r] = (__bf16)fmaxf(acc2[mt][nt][r] + b2r[mt][r], 0.f);
          *reinterpret_cast<bf16x4*>(&sh2[nt * 16 + nn][w * 32 + mt * 16 + q * 4]) = pk;
        }
    }
    __syncthreads();

    // ---- layer 3: (32x128) @ (128x256) ----
    f32x4 acc3[4][2];
    #pragma unroll
    for (int mt = 0; mt < 4; ++mt)
      #pragma unroll
      for (int nt = 0; nt < 2; ++nt) acc3[mt][nt] = zero4;
    #pragma unroll
    for (int ks = 0; ks < 4; ++ks) {
      bf16x8 bfr[2];
      #pragma unroll
      for (int nt = 0; nt < 2; ++nt)
        bfr[nt] = *reinterpret_cast<const bf16x8*>(&sh2[nt * 16 + nn][ks * 32 + q * 8]);
      #pragma unroll
      for (int mt = 0; mt < 4; ++mt)
        #pragma unroll
        for (int nt = 0; nt < 2; ++nt)
          acc3[mt][nt] = __builtin_amdgcn_mfma_f32_16x16x32_bf16(w3f[mt][ks], bfr[nt], acc3[mt][nt], 0, 0, 0);
    }

    // ---- segment max (sorted ids; block-uniform control) ----
    int smin = segt[0], smax = segt[MT - 1];
    if (smin != s_cur) {           // previous segment ended exactly at tile edge
      flushvals(run, s_cur);
      #pragma unroll
      for (int mt = 0; mt < 4; ++mt)
        #pragma unroll
        for (int r = 0; r < 4; ++r) run[mt][r] = -FLT_MAX;
      s_cur = smin;
    }
    if (smin == smax) {
      // fast path: whole tile in one segment -> fold into register running max
      #pragma unroll
      for (int mt = 0; mt < 4; ++mt)
        #pragma unroll
        for (int r = 0; r < 4; ++r)
          run[mt][r] = fmaxf(run[mt][r], fmaxf(acc3[mt][0][r], acc3[mt][1][r]));
    } else {
      // slow path: tile crosses >=1 boundary (~255 occurrences total)
      int sg0 = segt[nn], sg1 = segt[16 + nn];
      for (int s = smin; s <= smax; ++s) {
        float tmp[4][4];
        #pragma unroll
        for (int mt = 0; mt < 4; ++mt)
          #pragma unroll
          for (int r = 0; r < 4; ++r) {
            float v0 = (sg0 == s) ? acc3[mt][0][r] : -FLT_MAX;
            float v1 = (sg1 == s) ? acc3[mt][1][r] : -FLT_MAX;
            tmp[mt][r] = fmaxf(v0, v1);
          }
        if (s < smax) {
          if (s == s_cur) {
            #pragma unroll
            for (int mt = 0; mt < 4; ++mt)
              #pragma unroll
              for (int r = 0; r < 4; ++r) run[mt][r] = fmaxf(run[mt][r], tmp[mt][r]);
            flushvals(run, s);
            #pragma unroll
            for (int mt = 0; mt < 4; ++mt)
              #pragma unroll
              for (int r = 0; r < 4; ++r) run[mt][r] = -FLT_MAX;
          } else {
            flushvals(tmp, s);
          }
        } else {
          #pragma unroll
          for (int mt = 0; mt < 4; ++mt)
            #pragma unroll
            for (int r = 0; r < 4; ++r) run[mt][r] = fmaxf(run[mt][r], tmp[mt][r]);
        }
      }
      s_cur = smax;
    }
    __syncthreads();   // protect shF/segt/sh1/sh2 against next iteration's writes
  }
  flushvals(run, s_cur);
}

// ---------------- head: pooled @ Wf + bf -> softplus, + centroid ----------------
__global__ void final_kernel(const float* __restrict__ sums, const unsigned* __restrict__ pooled,
                             const float* __restrict__ Wf, const float* __restrict__ bfv,
                             float* __restrict__ out) {
  __shared__ float red[4][3];
  int g = blockIdx.x;
  int t = threadIdx.x;   // 256 = LAT
  unsigned u = pooled[g * LAT + t];
  float f = u ? unmapf(u) : 0.f;
  float s0 = f * Wf[t * 3 + 0];
  float s1 = f * Wf[t * 3 + 1];
  float s2 = f * Wf[t * 3 + 2];
  #pragma unroll
  for (int off = 1; off < 64; off <<= 1) {
    s0 += __shfl_xor(s0, off);
    s1 += __shfl_xor(s1, off);
    s2 += __shfl_xor(s2, off);
  }
  int wave = t >> 6;
  if ((t & 63) == 0) { red[wave][0] = s0; red[wave][1] = s1; red[wave][2] = s2; }
  __syncthreads();
  if (t < 3) {
    float acc = bfv[t] + red[0][t] + red[1][t] + red[2][t] + red[3][t];
    float sp  = fmaxf(acc, 0.f) + log1pf(expf(-fabsf(acc)));
    float cnt = fmaxf(sums[g * 4 + 3], 1.f);
    float cen = sums[g * 4 + t] / cnt;
    out[g * 3 + t] = cen + sp;
  }
}

extern "C" void kernel_launch(void* const* d_in, const int* in_sizes, int n_in,
                              void* d_out, int out_size, void* d_ws, size_t ws_size,
                              hipStream_t stream) {
  const float* pc  = (const float*)d_in[0];
  const float* W1  = (const float*)d_in[1];
  const float* b1  = (const float*)d_in[2];
  const float* W2  = (const float*)d_in[3];
  const float* b2  = (const float*)d_in[4];
  const float* W3  = (const float*)d_in[5];
  const float* b3  = (const float*)d_in[6];
  const float* Wf  = (const float*)d_in[7];
  const float* bfv = (const float*)d_in[8];
  const int*   sid = (const int*)d_in[9];
  int n = in_sizes[0] / 5;

  float*    sums   = (float*)d_ws;                         // G*4 fp32
  unsigned* pooled = (unsigned*)((char*)d_ws + 4096);      // G*LAT mapped-uint maxes
  hipMemsetAsync(d_ws, 0, 4096 + (size_t)G * LAT * 4, stream);

  centroid_kernel<<<512, 256, 0, stream>>>(pc, sid, sums, n);

  int tiles   = (n + MT - 1) / MT;
  int nblocks = 768;                         // 3 blocks/CU at __launch_bounds__(256,3)
  int tpb     = (tiles + nblocks - 1) / nblocks;
  mlp_kernel<<<nblocks, 256, 0, stream>>>(pc, W1, b1, W2, b2, W3, b3, sid, pooled, n, tpb);

  final_kernel<<<G, 256, 0, stream>>>(sums, pooled, Wf, bfv, (float*)d_out);
}

// Round 3
// 302.371 us; speedup vs baseline: 1.0400x; 1.0136x over previous
//
#include <hip/hip_runtime.h>
#include <float.h>

typedef __bf16 bf16x8 __attribute__((ext_vector_type(8)));
typedef __bf16 bf16x4 __attribute__((ext_vector_type(4)));
typedef float  f32x4  __attribute__((ext_vector_type(4)));

#define G      256
#define MT     32      // points per tile
#define H1DIM  64
#define H2DIM  128
#define LAT    256
#define H1PAD  72      // 144 B rows: 16B-aligned, 36 dw == 4 mod 32 -> conflict-free b128
#define H2PAD  136     // 272 B rows: 16B-aligned, 68 dw == 4 mod 32 -> conflict-free b128

// order-preserving float->uint map: max on uints == max on floats
__device__ __forceinline__ unsigned mapf(float f) {
  unsigned u = __float_as_uint(f);
  return (u & 0x80000000u) ? ~u : (u | 0x80000000u);
}
__device__ __forceinline__ float unmapf(unsigned u) {
  return (u & 0x80000000u) ? __uint_as_float(u & 0x7fffffffu) : __uint_as_float(~u);
}

// ---------------- centroids: segment mean of pos (cols 1..3) ----------------
__global__ void centroid_kernel(const float* __restrict__ pc, const int* __restrict__ sid,
                                float* __restrict__ sums, int n) {
  __shared__ float ls[G * 4];
  for (int i = threadIdx.x; i < G * 4; i += blockDim.x) ls[i] = 0.f;
  __syncthreads();
  int stride = gridDim.x * blockDim.x;
  for (int p = blockIdx.x * blockDim.x + threadIdx.x; p < n; p += stride) {
    int s = sid[p];
    float px = pc[p * 5 + 1], py = pc[p * 5 + 2], pz = pc[p * 5 + 3];
    int s0 = __shfl(s, 0);
    unsigned long long bal = __ballot(s == s0);
    if (bal == ~0ull) {   // whole wave same segment (sorted ids)
      #pragma unroll
      for (int off = 1; off < 64; off <<= 1) {
        px += __shfl_xor(px, off);
        py += __shfl_xor(py, off);
        pz += __shfl_xor(pz, off);
      }
      if ((threadIdx.x & 63) == 0) {
        atomicAdd(&ls[s0 * 4 + 0], px);
        atomicAdd(&ls[s0 * 4 + 1], py);
        atomicAdd(&ls[s0 * 4 + 2], pz);
        atomicAdd(&ls[s0 * 4 + 3], 64.f);
      }
    } else {
      atomicAdd(&ls[s * 4 + 0], px);
      atomicAdd(&ls[s * 4 + 1], py);
      atomicAdd(&ls[s * 4 + 2], pz);
      atomicAdd(&ls[s * 4 + 3], 1.f);
    }
  }
  __syncthreads();
  for (int i = threadIdx.x; i < G * 4; i += blockDim.x)
    if (ls[i] != 0.f) atomicAdd(&sums[i], ls[i]);
}

// flush helper: vectors passed BY VALUE (no address-taken on caller arrays -> no scratch).
// Reduces over the 16 point-lanes, adds bias, atomicMax to global pooled[s].
__device__ __forceinline__ void flush4(f32x4 v0, f32x4 v1, f32x4 v2, f32x4 v3,
                                       int s, int w, int q, int nn,
                                       const float* __restrict__ b3,
                                       unsigned* __restrict__ pooled) {
  f32x4 vv[4] = {v0, v1, v2, v3};
  #pragma unroll
  for (int mt = 0; mt < 4; ++mt)
    #pragma unroll
    for (int r = 0; r < 4; ++r) {
      int feat = w * 64 + mt * 16 + q * 4 + r;
      float v = vv[mt][r] + b3[feat];
      v = fmaxf(v, __shfl_xor(v, 1));
      v = fmaxf(v, __shfl_xor(v, 2));
      v = fmaxf(v, __shfl_xor(v, 4));
      v = fmaxf(v, __shfl_xor(v, 8));
      if (nn == 0) atomicMax(&pooled[s * LAT + feat], mapf(v));
    }
}

// ---------------- fused MLP + segment max ----------------
// 256 thr = 4 waves. A-operand = weights (registers), B-operand = activations (LDS).
// Wave w owns out-features: L1 [w*16,+16), L2 [w*32,+32), L3 [w*64,+64); all 32 points.
// C/D layout: row (q*4+r) = out-feature, col (nn) = point -> packed b64 epilogue writes.
__global__ __launch_bounds__(256, 3) void mlp_kernel(
    const float* __restrict__ pc,
    const float* __restrict__ W1, const float* __restrict__ b1,
    const float* __restrict__ W2, const float* __restrict__ b2,
    const float* __restrict__ W3, const float* __restrict__ b3,
    const int* __restrict__ sid,
    unsigned* __restrict__ pooled,
    int n, int tiles_per_block) {
  __shared__ __align__(16) __bf16 shF[MT][8];
  __shared__ __align__(16) __bf16 sh1[MT][H1PAD];
  __shared__ __align__(16) __bf16 sh2[MT][H2PAD];
  __shared__ int segt[MT];

  const int t  = threadIdx.x;
  const int w  = t >> 6;         // wave id 0..3
  const int lane = t & 63;
  const int q  = lane >> 4;
  const int nn = lane & 15;

  // ---- persistent weight fragments (A-operand: A[m=nn][k=q*8+j]) ----
  bf16x8 w1f;                    // L1, K=32 zero-padded (real K=4)
  #pragma unroll
  for (int j = 0; j < 8; ++j) {
    int k = q * 8 + j;
    w1f[j] = (k < 4) ? (__bf16)W1[k * H1DIM + w * 16 + nn] : (__bf16)0.f;
  }
  float b1r[4];
  #pragma unroll
  for (int r = 0; r < 4; ++r) b1r[r] = b1[w * 16 + q * 4 + r];

  bf16x8 w2f[2][2];              // [mt][ks]
  float  b2r[2][4];
  #pragma unroll
  for (int mt = 0; mt < 2; ++mt) {
    int m = w * 32 + mt * 16 + nn;
    #pragma unroll
    for (int ks = 0; ks < 2; ++ks)
      #pragma unroll
      for (int j = 0; j < 8; ++j)
        w2f[mt][ks][j] = (__bf16)W2[(ks * 32 + q * 8 + j) * H2DIM + m];
    #pragma unroll
    for (int r = 0; r < 4; ++r) b2r[mt][r] = b2[w * 32 + mt * 16 + q * 4 + r];
  }

  bf16x8 w3f[4][4];              // [mt][ks]
  #pragma unroll
  for (int mt = 0; mt < 4; ++mt) {
    int m = w * 64 + mt * 16 + nn;
    #pragma unroll
    for (int ks = 0; ks < 4; ++ks)
      #pragma unroll
      for (int j = 0; j < 8; ++j)
        w3f[mt][ks][j] = (__bf16)W3[(ks * 32 + q * 8 + j) * LAT + m];
  }

  const f32x4 zero4 = {0.f, 0.f, 0.f, 0.f};
  const bf16x8 zero8 = {};
  const f32x4 neginf4 = {-FLT_MAX, -FLT_MAX, -FLT_MAX, -FLT_MAX};

  f32x4 run[4];                  // running segment max (bias NOT included)
  #pragma unroll
  for (int mt = 0; mt < 4; ++mt) run[mt] = neginf4;

  const int tile0 = blockIdx.x * tiles_per_block;
  int first = tile0 * MT; if (first > n - 1) first = n - 1;
  int s_cur = sid[first];

  for (int ti = 0; ti < tiles_per_block; ++ti) {
    const int base = (tile0 + ti) * MT;
    if (base >= n) break;

    // ---- stage 32 points (clamped duplicates are harmless for max) ----
    if (t < MT) {
      int p = base + t;
      int pcl = (p < n) ? p : (n - 1);
      const float* pp = pc + (size_t)pcl * 5;
      bf16x8 v = {};
      v[0] = (__bf16)pp[4];   // x first (concat order!)
      v[1] = (__bf16)pp[1];
      v[2] = (__bf16)pp[2];
      v[3] = (__bf16)pp[3];
      *reinterpret_cast<bf16x8*>(&shF[t][0]) = v;
      segt[t] = sid[pcl];
    }
    __syncthreads();

    // ---- layer 1 (MFMA, K zero-padded) ----
    {
      f32x4 acc1[2];
      #pragma unroll
      for (int nt = 0; nt < 2; ++nt) {
        bf16x8 ld = *reinterpret_cast<const bf16x8*>(&shF[nt * 16 + nn][0]);
        bf16x8 af = (q == 0) ? ld : zero8;
        acc1[nt] = __builtin_amdgcn_mfma_f32_16x16x32_bf16(w1f, af, zero4, 0, 0, 0);
      }
      #pragma unroll
      for (int nt = 0; nt < 2; ++nt) {
        bf16x4 pk;
        #pragma unroll
        for (int r = 0; r < 4; ++r)
          pk[r] = (__bf16)fmaxf(acc1[nt][r] + b1r[r], 0.f);
        *reinterpret_cast<bf16x4*>(&sh1[nt * 16 + nn][w * 16 + q * 4]) = pk;
      }
    }
    __syncthreads();

    // ---- layer 2: (32x64) @ (64x128) ----
    {
      f32x4 acc2[2][2];
      #pragma unroll
      for (int mt = 0; mt < 2; ++mt)
        #pragma unroll
        for (int nt = 0; nt < 2; ++nt) acc2[mt][nt] = zero4;
      #pragma unroll
      for (int ks = 0; ks < 2; ++ks) {
        bf16x8 bfr[2];
        #pragma unroll
        for (int nt = 0; nt < 2; ++nt)
          bfr[nt] = *reinterpret_cast<const bf16x8*>(&sh1[nt * 16 + nn][ks * 32 + q * 8]);
        #pragma unroll
        for (int mt = 0; mt < 2; ++mt)
          #pragma unroll
          for (int nt = 0; nt < 2; ++nt)
            acc2[mt][nt] = __builtin_amdgcn_mfma_f32_16x16x32_bf16(w2f[mt][ks], bfr[nt], acc2[mt][nt], 0, 0, 0);
      }
      #pragma unroll
      for (int mt = 0; mt < 2; ++mt)
        #pragma unroll
        for (int nt = 0; nt < 2; ++nt) {
          bf16x4 pk;
          #pragma unroll
          for (int r = 0; r < 4; ++r)
            pk[r] = (__bf16)fmaxf(acc2[mt][nt][r] + b2r[mt][r], 0.f);
          *reinterpret_cast<bf16x4*>(&sh2[nt * 16 + nn][w * 32 + mt * 16 + q * 4]) = pk;
        }
    }
    __syncthreads();

    // ---- layer 3: (32x128) @ (128x256) ----
    f32x4 acc3[4][2];
    #pragma unroll
    for (int mt = 0; mt < 4; ++mt)
      #pragma unroll
      for (int nt = 0; nt < 2; ++nt) acc3[mt][nt] = zero4;
    #pragma unroll
    for (int ks = 0; ks < 4; ++ks) {
      bf16x8 bfr[2];
      #pragma unroll
      for (int nt = 0; nt < 2; ++nt)
        bfr[nt] = *reinterpret_cast<const bf16x8*>(&sh2[nt * 16 + nn][ks * 32 + q * 8]);
      #pragma unroll
      for (int mt = 0; mt < 4; ++mt)
        #pragma unroll
        for (int nt = 0; nt < 2; ++nt)
          acc3[mt][nt] = __builtin_amdgcn_mfma_f32_16x16x32_bf16(w3f[mt][ks], bfr[nt], acc3[mt][nt], 0, 0, 0);
    }

    // ---- segment max (sorted ids; block-uniform control) ----
    int smin = segt[0], smax = segt[MT - 1];
    if (smin != s_cur) {           // previous segment ended exactly at tile edge
      flush4(run[0], run[1], run[2], run[3], s_cur, w, q, nn, b3, pooled);
      #pragma unroll
      for (int mt = 0; mt < 4; ++mt) run[mt] = neginf4;
      s_cur = smin;
    }
    if (smin == smax) {
      // fast path: whole tile in one segment -> fold into register running max
      #pragma unroll
      for (int mt = 0; mt < 4; ++mt)
        #pragma unroll
        for (int r = 0; r < 4; ++r)
          run[mt][r] = fmaxf(run[mt][r], fmaxf(acc3[mt][0][r], acc3[mt][1][r]));
    } else {
      // slow path: tile crosses >=1 boundary (~255 occurrences total)
      int sg0 = segt[nn], sg1 = segt[16 + nn];
      for (int s = smin; s <= smax; ++s) {
        f32x4 tmp[4];
        #pragma unroll
        for (int mt = 0; mt < 4; ++mt)
          #pragma unroll
          for (int r = 0; r < 4; ++r) {
            float v0 = (sg0 == s) ? acc3[mt][0][r] : -FLT_MAX;
            float v1 = (sg1 == s) ? acc3[mt][1][r] : -FLT_MAX;
            tmp[mt][r] = fmaxf(v0, v1);
          }
        if (s < smax) {
          if (s == s_cur) {
            #pragma unroll
            for (int mt = 0; mt < 4; ++mt)
              #pragma unroll
              for (int r = 0; r < 4; ++r) run[mt][r] = fmaxf(run[mt][r], tmp[mt][r]);
            flush4(run[0], run[1], run[2], run[3], s, w, q, nn, b3, pooled);
            #pragma unroll
            for (int mt = 0; mt < 4; ++mt) run[mt] = neginf4;
          } else {
            flush4(tmp[0], tmp[1], tmp[2], tmp[3], s, w, q, nn, b3, pooled);
          }
        } else {
          #pragma unroll
          for (int mt = 0; mt < 4; ++mt)
            #pragma unroll
            for (int r = 0; r < 4; ++r) run[mt][r] = fmaxf(run[mt][r], tmp[mt][r]);
        }
      }
      s_cur = smax;
    }
    __syncthreads();   // protect shF/segt/sh1/sh2 against next iteration's writes
  }
  flush4(run[0], run[1], run[2], run[3], s_cur, w, q, nn, b3, pooled);
}

// ---------------- head: pooled @ Wf + bf -> softplus, + centroid ----------------
__global__ void final_kernel(const float* __restrict__ sums, const unsigned* __restrict__ pooled,
                             const float* __restrict__ Wf, const float* __restrict__ bfv,
                             float* __restrict__ out) {
  __shared__ float red[4][3];
  int g = blockIdx.x;
  int t = threadIdx.x;   // 256 = LAT
  unsigned u = pooled[g * LAT + t];
  float f = u ? unmapf(u) : 0.f;
  float s0 = f * Wf[t * 3 + 0];
  float s1 = f * Wf[t * 3 + 1];
  float s2 = f * Wf[t * 3 + 2];
  #pragma unroll
  for (int off = 1; off < 64; off <<= 1) {
    s0 += __shfl_xor(s0, off);
    s1 += __shfl_xor(s1, off);
    s2 += __shfl_xor(s2, off);
  }
  int wave = t >> 6;
  if ((t & 63) == 0) { red[wave][0] = s0; red[wave][1] = s1; red[wave][2] = s2; }
  __syncthreads();
  if (t < 3) {
    float acc = bfv[t] + red[0][t] + red[1][t] + red[2][t] + red[3][t];
    float sp  = fmaxf(acc, 0.f) + log1pf(expf(-fabsf(acc)));
    float cnt = fmaxf(sums[g * 4 + 3], 1.f);
    float cen = sums[g * 4 + t] / cnt;
    out[g * 3 + t] = cen + sp;
  }
}

extern "C" void kernel_launch(void* const* d_in, const int* in_sizes, int n_in,
                              void* d_out, int out_size, void* d_ws, size_t ws_size,
                              hipStream_t stream) {
  const float* pc  = (const float*)d_in[0];
  const float* W1  = (const float*)d_in[1];
  const float* b1  = (const float*)d_in[2];
  const float* W2  = (const float*)d_in[3];
  const float* b2  = (const float*)d_in[4];
  const float* W3  = (const float*)d_in[5];
  const float* b3  = (const float*)d_in[6];
  const float* Wf  = (const float*)d_in[7];
  const float* bfv = (const float*)d_in[8];
  const int*   sid = (const int*)d_in[9];
  int n = in_sizes[0] / 5;

  float*    sums   = (float*)d_ws;                         // G*4 fp32
  unsigned* pooled = (unsigned*)((char*)d_ws + 4096);      // G*LAT mapped-uint maxes
  hipMemsetAsync(d_ws, 0, 4096 + (size_t)G * LAT * 4, stream);

  centroid_kernel<<<512, 256, 0, stream>>>(pc, sid, sums, n);

  int tiles   = (n + MT - 1) / MT;
  int nblocks = 768;                         // 3 blocks/CU at __launch_bounds__(256,3)
  int tpb     = (tiles + nblocks - 1) / nblocks;
  mlp_kernel<<<nblocks, 256, 0, stream>>>(pc, W1, b1, W2, b2, W3, b3, sid, pooled, n, tpb);

  final_kernel<<<G, 256, 0, stream>>>(sums, pooled, Wf, bfv, (float*)d_out);
}

// Round 4
// 224.940 us; speedup vs baseline: 1.3980x; 1.3442x over previous
//
#include <hip/hip_runtime.h>
#include <float.h>

typedef __bf16 bf16x8 __attribute__((ext_vector_type(8)));
typedef __bf16 bf16x4 __attribute__((ext_vector_type(4)));
typedef float  f32x4  __attribute__((ext_vector_type(4)));

#define G      256
#define MT     32      // points per tile
#define H1DIM  64
#define H2DIM  128
#define LAT    256
#define H1PAD  72      // 144 B rows: 16B-aligned, 36 dw == 4 mod 32 -> 2-way (free) b128
#define H2PAD  136     // 272 B rows: 16B-aligned, 68 dw == 4 mod 32 -> 2-way (free) b128

// order-preserving float->uint map: max on uints == max on floats
__device__ __forceinline__ unsigned mapf(float f) {
  unsigned u = __float_as_uint(f);
  return (u & 0x80000000u) ? ~u : (u | 0x80000000u);
}
__device__ __forceinline__ float unmapf(unsigned u) {
  return (u & 0x80000000u) ? __uint_as_float(u & 0x7fffffffu) : __uint_as_float(~u);
}

// flush helper: vectors passed BY VALUE (no address-taken on caller arrays).
// Reduces over the 16 point-lanes, adds bias, atomicMax to global pooled[s].
__device__ __forceinline__ void flush4(f32x4 v0, f32x4 v1, f32x4 v2, f32x4 v3,
                                       int s, int w, int q, int nn,
                                       const float* __restrict__ b3,
                                       unsigned* __restrict__ pooled) {
  f32x4 vv[4] = {v0, v1, v2, v3};
  #pragma unroll
  for (int mt = 0; mt < 4; ++mt)
    #pragma unroll
    for (int r = 0; r < 4; ++r) {
      int feat = w * 64 + mt * 16 + q * 4 + r;
      float v = vv[mt][r] + b3[feat];
      v = fmaxf(v, __shfl_xor(v, 1));
      v = fmaxf(v, __shfl_xor(v, 2));
      v = fmaxf(v, __shfl_xor(v, 4));
      v = fmaxf(v, __shfl_xor(v, 8));
      if (nn == 0) atomicMax(&pooled[s * LAT + feat], mapf(v));
    }
}

// ---------------- fused centroid + MLP + segment max ----------------
// 256 thr = 4 waves. A-operand = weights (registers), B-operand = activations (LDS).
// Wave w owns out-features: L1 [w*16,+16), L2 [w*32,+32), L3 [w*64,+64); all 32 points.
// C/D layout: row (q*4+r) = out-feature, col (nn) = point -> packed b64 epilogue writes.
// Centroids: staging threads (t<32) keep fp32 running sums, flush on seg transition.
// __launch_bounds__(256,2): 256-reg cap. (256,3) capped at 168 and forced ~20 regs
// to scratch (VGPR 84+84 AGPR, 49 MB/dispatch extra HBM) -- spill-free wins.
__global__ __launch_bounds__(256, 2) void mlp_kernel(
    const float* __restrict__ pc,
    const float* __restrict__ W1, const float* __restrict__ b1,
    const float* __restrict__ W2, const float* __restrict__ b2,
    const float* __restrict__ W3, const float* __restrict__ b3,
    const int* __restrict__ sid,
    unsigned* __restrict__ pooled,
    float* __restrict__ sums,
    int n, int tiles_per_block) {
  __shared__ __align__(16) __bf16 shF[MT][8];
  __shared__ __align__(16) __bf16 sh1[MT][H1PAD];
  __shared__ __align__(16) __bf16 sh2[MT][H2PAD];
  __shared__ int segt[MT];

  const int t  = threadIdx.x;
  const int w  = t >> 6;         // wave id 0..3
  const int lane = t & 63;
  const int q  = lane >> 4;
  const int nn = lane & 15;

  // ---- persistent weight fragments (A-operand: A[m=nn][k=q*8+j]) ----
  bf16x8 w1f;                    // L1, K=32 zero-padded (real K=4)
  #pragma unroll
  for (int j = 0; j < 8; ++j) {
    int k = q * 8 + j;
    w1f[j] = (k < 4) ? (__bf16)W1[k * H1DIM + w * 16 + nn] : (__bf16)0.f;
  }
  float b1r[4];
  #pragma unroll
  for (int r = 0; r < 4; ++r) b1r[r] = b1[w * 16 + q * 4 + r];

  bf16x8 w2f[2][2];              // [mt][ks]
  float  b2r[2][4];
  #pragma unroll
  for (int mt = 0; mt < 2; ++mt) {
    int m = w * 32 + mt * 16 + nn;
    #pragma unroll
    for (int ks = 0; ks < 2; ++ks)
      #pragma unroll
      for (int j = 0; j < 8; ++j)
        w2f[mt][ks][j] = (__bf16)W2[(ks * 32 + q * 8 + j) * H2DIM + m];
    #pragma unroll
    for (int r = 0; r < 4; ++r) b2r[mt][r] = b2[w * 32 + mt * 16 + q * 4 + r];
  }

  bf16x8 w3f[4][4];              // [mt][ks]
  #pragma unroll
  for (int mt = 0; mt < 4; ++mt) {
    int m = w * 64 + mt * 16 + nn;
    #pragma unroll
    for (int ks = 0; ks < 4; ++ks)
      #pragma unroll
      for (int j = 0; j < 8; ++j)
        w3f[mt][ks][j] = (__bf16)W3[(ks * 32 + q * 8 + j) * LAT + m];
  }

  const f32x4 zero4 = {0.f, 0.f, 0.f, 0.f};
  const bf16x8 zero8 = {};
  const f32x4 neginf4 = {-FLT_MAX, -FLT_MAX, -FLT_MAX, -FLT_MAX};

  f32x4 run[4];                  // running segment max (bias NOT included)
  #pragma unroll
  for (int mt = 0; mt < 4; ++mt) run[mt] = neginf4;

  // centroid accumulation state (staging threads t<32 only)
  float cx = 0.f, cy = 0.f, cz = 0.f, cc = 0.f;
  int   cseg = -1;

  const int tile0 = blockIdx.x * tiles_per_block;
  int first = tile0 * MT; if (first > n - 1) first = n - 1;
  int s_cur = sid[first];

  for (int ti = 0; ti < tiles_per_block; ++ti) {
    const int base = (tile0 + ti) * MT;
    if (base >= n) break;

    // ---- stage 32 points (clamped duplicates are harmless for max) ----
    if (t < MT) {
      int p = base + t;
      bool valid = p < n;
      int pcl = valid ? p : (n - 1);
      const float* pp = pc + (size_t)pcl * 5;
      float fx = pp[4], p1 = pp[1], p2 = pp[2], p3 = pp[3];
      bf16x8 v = {};
      v[0] = (__bf16)fx;   // x first (concat order!)
      v[1] = (__bf16)p1;
      v[2] = (__bf16)p2;
      v[3] = (__bf16)p3;
      *reinterpret_cast<bf16x8*>(&shF[t][0]) = v;
      int s = sid[pcl];
      segt[t] = s;
      if (valid) {
        if (s != cseg) {
          if (cc > 0.f) {
            atomicAdd(&sums[cseg * 4 + 0], cx);
            atomicAdd(&sums[cseg * 4 + 1], cy);
            atomicAdd(&sums[cseg * 4 + 2], cz);
            atomicAdd(&sums[cseg * 4 + 3], cc);
          }
          cseg = s; cx = 0.f; cy = 0.f; cz = 0.f; cc = 0.f;
        }
        cx += p1; cy += p2; cz += p3; cc += 1.f;
      }
    }
    __syncthreads();

    // ---- layer 1 (MFMA, K zero-padded) ----
    {
      f32x4 acc1[2];
      #pragma unroll
      for (int nt = 0; nt < 2; ++nt) {
        bf16x8 ld = *reinterpret_cast<const bf16x8*>(&shF[nt * 16 + nn][0]);
        bf16x8 af = (q == 0) ? ld : zero8;
        acc1[nt] = __builtin_amdgcn_mfma_f32_16x16x32_bf16(w1f, af, zero4, 0, 0, 0);
      }
      #pragma unroll
      for (int nt = 0; nt < 2; ++nt) {
        bf16x4 pk;
        #pragma unroll
        for (int r = 0; r < 4; ++r)
          pk[r] = (__bf16)fmaxf(acc1[nt][r] + b1r[r], 0.f);
        *reinterpret_cast<bf16x4*>(&sh1[nt * 16 + nn][w * 16 + q * 4]) = pk;
      }
    }
    __syncthreads();

    // ---- layer 2: (32x64) @ (64x128) ----
    {
      f32x4 acc2[2][2];
      #pragma unroll
      for (int mt = 0; mt < 2; ++mt)
        #pragma unroll
        for (int nt = 0; nt < 2; ++nt) acc2[mt][nt] = zero4;
      #pragma unroll
      for (int ks = 0; ks < 2; ++ks) {
        bf16x8 bfr[2];
        #pragma unroll
        for (int nt = 0; nt < 2; ++nt)
          bfr[nt] = *reinterpret_cast<const bf16x8*>(&sh1[nt * 16 + nn][ks * 32 + q * 8]);
        #pragma unroll
        for (int mt = 0; mt < 2; ++mt)
          #pragma unroll
          for (int nt = 0; nt < 2; ++nt)
            acc2[mt][nt] = __builtin_amdgcn_mfma_f32_16x16x32_bf16(w2f[mt][ks], bfr[nt], acc2[mt][nt], 0, 0, 0);
      }
      #pragma unroll
      for (int mt = 0; mt < 2; ++mt)
        #pragma unroll
        for (int nt = 0; nt < 2; ++nt) {
          bf16x4 pk;
          #pragma unroll
          for (int r = 0; r < 4; ++r)
            pk[r] = (__bf16)fmaxf(acc2[mt][nt][r] + b2r[mt][r], 0.f);
          *reinterpret_cast<bf16x4*>(&sh2[nt * 16 + nn][w * 32 + mt * 16 + q * 4]) = pk;
        }
    }
    __syncthreads();

    // ---- layer 3: (32x128) @ (128x256) ----
    f32x4 acc3[4][2];
    #pragma unroll
    for (int mt = 0; mt < 4; ++mt)
      #pragma unroll
      for (int nt = 0; nt < 2; ++nt) acc3[mt][nt] = zero4;
    #pragma unroll
    for (int ks = 0; ks < 4; ++ks) {
      bf16x8 bfr[2];
      #pragma unroll
      for (int nt = 0; nt < 2; ++nt)
        bfr[nt] = *reinterpret_cast<const bf16x8*>(&sh2[nt * 16 + nn][ks * 32 + q * 8]);
      #pragma unroll
      for (int mt = 0; mt < 4; ++mt)
        #pragma unroll
        for (int nt = 0; nt < 2; ++nt)
          acc3[mt][nt] = __builtin_amdgcn_mfma_f32_16x16x32_bf16(w3f[mt][ks], bfr[nt], acc3[mt][nt], 0, 0, 0);
    }

    // ---- segment max (sorted ids; block-uniform control) ----
    int smin = segt[0], smax = segt[MT - 1];
    if (smin != s_cur) {           // previous segment ended exactly at tile edge
      flush4(run[0], run[1], run[2], run[3], s_cur, w, q, nn, b3, pooled);
      #pragma unroll
      for (int mt = 0; mt < 4; ++mt) run[mt] = neginf4;
      s_cur = smin;
    }
    if (smin == smax) {
      // fast path: whole tile in one segment -> fold into register running max
      #pragma unroll
      for (int mt = 0; mt < 4; ++mt)
        #pragma unroll
        for (int r = 0; r < 4; ++r)
          run[mt][r] = fmaxf(run[mt][r], fmaxf(acc3[mt][0][r], acc3[mt][1][r]));
    } else {
      // slow path: tile crosses >=1 boundary (~255 occurrences total)
      int sg0 = segt[nn], sg1 = segt[16 + nn];
      for (int s = smin; s <= smax; ++s) {
        f32x4 tmp[4];
        #pragma unroll
        for (int mt = 0; mt < 4; ++mt)
          #pragma unroll
          for (int r = 0; r < 4; ++r) {
            float v0 = (sg0 == s) ? acc3[mt][0][r] : -FLT_MAX;
            float v1 = (sg1 == s) ? acc3[mt][1][r] : -FLT_MAX;
            tmp[mt][r] = fmaxf(v0, v1);
          }
        if (s < smax) {
          if (s == s_cur) {
            #pragma unroll
            for (int mt = 0; mt < 4; ++mt)
              #pragma unroll
              for (int r = 0; r < 4; ++r) run[mt][r] = fmaxf(run[mt][r], tmp[mt][r]);
            flush4(run[0], run[1], run[2], run[3], s, w, q, nn, b3, pooled);
            #pragma unroll
            for (int mt = 0; mt < 4; ++mt) run[mt] = neginf4;
          } else {
            flush4(tmp[0], tmp[1], tmp[2], tmp[3], s, w, q, nn, b3, pooled);
          }
        } else {
          #pragma unroll
          for (int mt = 0; mt < 4; ++mt)
            #pragma unroll
            for (int r = 0; r < 4; ++r) run[mt][r] = fmaxf(run[mt][r], tmp[mt][r]);
        }
      }
      s_cur = smax;
    }
    __syncthreads();   // protect shF/segt/sh1/sh2 against next iteration's writes
  }
  flush4(run[0], run[1], run[2], run[3], s_cur, w, q, nn, b3, pooled);

  // final centroid flush
  if (t < MT && cc > 0.f) {
    atomicAdd(&sums[cseg * 4 + 0], cx);
    atomicAdd(&sums[cseg * 4 + 1], cy);
    atomicAdd(&sums[cseg * 4 + 2], cz);
    atomicAdd(&sums[cseg * 4 + 3], cc);
  }
}

// ---------------- head: pooled @ Wf + bf -> softplus, + centroid ----------------
__global__ void final_kernel(const float* __restrict__ sums, const unsigned* __restrict__ pooled,
                             const float* __restrict__ Wf, const float* __restrict__ bfv,
                             float* __restrict__ out) {
  __shared__ float red[4][3];
  int g = blockIdx.x;
  int t = threadIdx.x;   // 256 = LAT
  unsigned u = pooled[g * LAT + t];
  float f = u ? unmapf(u) : 0.f;
  float s0 = f * Wf[t * 3 + 0];
  float s1 = f * Wf[t * 3 + 1];
  float s2 = f * Wf[t * 3 + 2];
  #pragma unroll
  for (int off = 1; off < 64; off <<= 1) {
    s0 += __shfl_xor(s0, off);
    s1 += __shfl_xor(s1, off);
    s2 += __shfl_xor(s2, off);
  }
  int wave = t >> 6;
  if ((t & 63) == 0) { red[wave][0] = s0; red[wave][1] = s1; red[wave][2] = s2; }
  __syncthreads();
  if (t < 3) {
    float acc = bfv[t] + red[0][t] + red[1][t] + red[2][t] + red[3][t];
    float sp  = fmaxf(acc, 0.f) + log1pf(expf(-fabsf(acc)));
    float cnt = fmaxf(sums[g * 4 + 3], 1.f);
    float cen = sums[g * 4 + t] / cnt;
    out[g * 3 + t] = cen + sp;
  }
}

extern "C" void kernel_launch(void* const* d_in, const int* in_sizes, int n_in,
                              void* d_out, int out_size, void* d_ws, size_t ws_size,
                              hipStream_t stream) {
  const float* pc  = (const float*)d_in[0];
  const float* W1  = (const float*)d_in[1];
  const float* b1  = (const float*)d_in[2];
  const float* W2  = (const float*)d_in[3];
  const float* b2  = (const float*)d_in[4];
  const float* W3  = (const float*)d_in[5];
  const float* b3  = (const float*)d_in[6];
  const float* Wf  = (const float*)d_in[7];
  const float* bfv = (const float*)d_in[8];
  const int*   sid = (const int*)d_in[9];
  int n = in_sizes[0] / 5;

  float*    sums   = (float*)d_ws;                         // G*4 fp32
  unsigned* pooled = (unsigned*)((char*)d_ws + 4096);      // G*LAT mapped-uint maxes
  hipMemsetAsync(d_ws, 0, 4096 + (size_t)G * LAT * 4, stream);

  int tiles   = (n + MT - 1) / MT;
  int nblocks = 512;                         // 2 blocks/CU at __launch_bounds__(256,2)
  int tpb     = (tiles + nblocks - 1) / nblocks;
  mlp_kernel<<<nblocks, 256, 0, stream>>>(pc, W1, b1, W2, b2, W3, b3, sid, pooled, sums, n, tpb);

  final_kernel<<<G, 256, 0, stream>>>(sums, pooled, Wf, bfv, (float*)d_out);
}